// Round 3
// baseline (219.702 us; speedup 1.0000x reference)
//
#include <hip/hip_runtime.h>
#include <cstdint>

#define NTOT 73728      // B*H*W = 32*48*48
#define CTOT 512
#define MGRP 128        // members per group
#define EPSV 1e-7f
#define LDP  72         // LDS row stride in bf16 (144 B: 16B-aligned, 2-way banks on frag reads)

typedef float4 f4;
typedef __attribute__((ext_vector_type(8))) short bf16x8;   // 8 bf16 (4 VGPRs)
typedef __attribute__((ext_vector_type(4))) float f32x4;
typedef __attribute__((ext_vector_type(16))) float f32x16;

__device__ __forceinline__ f4 ld4(const float* p){ return *(const f4*)p; }

__device__ __forceinline__ ushort f2bf(float f){  // RNE fp32 -> bf16
    uint32_t u = __builtin_bit_cast(uint32_t, f);
    uint32_t r = (u + 0x7FFFu + ((u >> 16) & 1u)) >> 16;
    return (ushort)r;
}

// ---------------- K1: per-chunk Sxx partials (MFMA) + Sx partials ----------------
// grid (nchunk, 4), block 512 (8 waves, 2x4; wave tile 64x32 of 128x128 output).
// K-tile = 64 samples staged in LDS as [channel][sample] bf16, stride LDP=72.
__global__ __launch_bounds__(512) void k_cov(
    const float* __restrict__ x, float* __restrict__ sxxPart,
    float* __restrict__ sxPart, int nchunk, int rowsPer)
{
    const int chunk = blockIdx.x, g = blockIdx.y;
    const int t = threadIdx.x;
    const int lane = t & 63, wid = t >> 6;
    const int wm = wid >> 2, wn = wid & 3;
    const int l15 = lane & 15, l4 = lane >> 4;

    __shared__ ushort xs[128 * LDP];     // 18,432 B
    __shared__ float sxbuf[512];

    const int c = t & 127;               // staging channel
    const int o = t >> 7;                // octet id: handles octets o and o+4
    const float* xp = x + (size_t)chunk * rowsPer * CTOT + (size_t)g * MGRP + c;

    f32x4 acc[4][2];
#pragma unroll
    for (int i = 0; i < 4; ++i)
#pragma unroll
        for (int j = 0; j < 2; ++j) acc[i][j] = (f32x4){0.f, 0.f, 0.f, 0.f};
    float sx = 0.f;

    float v[16];
#pragma unroll
    for (int e = 0; e < 8; ++e) {
        v[e]     = xp[(size_t)(o * 8 + e) * CTOT];
        v[8 + e] = xp[(size_t)((o + 4) * 8 + e) * CTOT];
    }

    const int niter = rowsPer / 64;
    for (int it = 0; it < niter; ++it) {
        uint32_t pkA[4], pkB[4];
#pragma unroll
        for (int e = 0; e < 4; ++e) {
            sx += v[2*e] + v[2*e+1] + v[8+2*e] + v[8+2*e+1];
            pkA[e] = (uint32_t)f2bf(v[2*e])   | ((uint32_t)f2bf(v[2*e+1])   << 16);
            pkB[e] = (uint32_t)f2bf(v[8+2*e]) | ((uint32_t)f2bf(v[8+2*e+1]) << 16);
        }
        if (it) __syncthreads();
        *(uint4*)&xs[c * LDP + o * 8]       = make_uint4(pkA[0], pkA[1], pkA[2], pkA[3]);
        *(uint4*)&xs[c * LDP + (o + 4) * 8] = make_uint4(pkB[0], pkB[1], pkB[2], pkB[3]);
        __syncthreads();
        if (it + 1 < niter) {
            const float* np = xp + (size_t)(it + 1) * 64 * CTOT;
#pragma unroll
            for (int e = 0; e < 8; ++e) {
                v[e]     = np[(size_t)(o * 8 + e) * CTOT];
                v[8 + e] = np[(size_t)((o + 4) * 8 + e) * CTOT];
            }
        }
#pragma unroll
        for (int kc = 0; kc < 2; ++kc) {
            bf16x8 af[4], bfr[2];
#pragma unroll
            for (int tm = 0; tm < 4; ++tm)
                af[tm] = *(const bf16x8*)&xs[(wm*64 + tm*16 + l15) * LDP + kc*32 + l4*8];
#pragma unroll
            for (int tn = 0; tn < 2; ++tn)
                bfr[tn] = *(const bf16x8*)&xs[(wn*32 + tn*16 + l15) * LDP + kc*32 + l4*8];
#pragma unroll
            for (int tm = 0; tm < 4; ++tm)
#pragma unroll
                for (int tn = 0; tn < 2; ++tn)
                    acc[tm][tn] = __builtin_amdgcn_mfma_f32_16x16x32_bf16(
                        af[tm], bfr[tn], acc[tm][tn], 0, 0, 0);
        }
    }

    float* op = sxxPart + ((size_t)g * nchunk + chunk) * 16384;
#pragma unroll
    for (int tm = 0; tm < 4; ++tm)
#pragma unroll
        for (int tn = 0; tn < 2; ++tn)
#pragma unroll
            for (int r = 0; r < 4; ++r) {
                int i = wm*64 + tm*16 + l4*4 + r;
                int j = wn*32 + tn*16 + l15;
                __builtin_nontemporal_store(acc[tm][tn][r], &op[i * 128 + j]);
            }

    sxbuf[t] = sx;
    __syncthreads();
    if (t < 128) {
        float s = sxbuf[t] + sxbuf[t + 128] + sxbuf[t + 256] + sxbuf[t + 384];
        sxPart[((size_t)g * nchunk + chunk) * 128 + t] = s;
    }
}

// ---------------- K2: reduce Sxx partials over chunks ----------------
__global__ __launch_bounds__(256) void k_reduce(
    const float* __restrict__ sxxPart, float* __restrict__ gSxx, int nchunk)
{
    int g = blockIdx.y;
    int idx = blockIdx.x * 256 + threadIdx.x;
    float s = 0.f;
#pragma unroll 8
    for (int c = 0; c < nchunk; ++c)
        s += __builtin_nontemporal_load(&sxxPart[((size_t)g * nchunk + c) * 16384 + idx]);
    gSxx[g * 16384 + idx] = s;
}

// ---------------- K3: finalize -> mean, trace, sigma, P1 ----------------
__global__ __launch_bounds__(256) void k_finalize(
    const float* __restrict__ gSxx, const float* __restrict__ sxPart,
    float* __restrict__ gSigma, float* __restrict__ gP,
    float* __restrict__ gMean, float* __restrict__ gScale, int nchunk)
{
    int g = blockIdx.x, t = threadIdx.x;
    __shared__ float mu[128];
    __shared__ float red[256];

    if (t < 128) {
        float s = 0.f;
        for (int c = 0; c < nchunk; ++c)
            s += sxPart[((size_t)g * nchunk + c) * 128 + t];
        float m = s / (float)NTOT;
        mu[t] = m;
        gMean[g * 128 + t] = m;
    }
    __syncthreads();

    float d = 0.f;
    if (t < 128) {
        float vdiag = gSxx[g * 16384 + t * 128 + t];
        float cv = (vdiag - (float)NTOT * mu[t] * mu[t]) / ((float)NTOT - 1.f);
        d = (1.f - EPSV) * cv + EPSV;
    }
    red[t] = d;
    __syncthreads();
    for (int s = 128; s > 0; s >>= 1) {
        if (t < s) red[t] += red[t + s];
        __syncthreads();
    }
    float tr = red[0];
    float invTr = 1.f / tr;
    if (t == 0) gScale[g] = rsqrtf(tr);

    for (int e = t; e < 16384; e += 256) {
        int i = e >> 7, j = e & 127;
        float cv = (gSxx[g * 16384 + e] - (float)NTOT * mu[i] * mu[j]) / ((float)NTOT - 1.f);
        float ce = (1.f - EPSV) * cv + ((i == j) ? EPSV : 0.f);
        float sg = ce * invTr;
        gSigma[g * 16384 + e] = sg;
        gP[g * 16384 + e] = ((i == j) ? 1.5f : 0.f) - 0.5f * sg;
    }
}

// ---------------- K4: P2 = P@P, PS = P@Sigma ----------------
__global__ __launch_bounds__(256) void k_ns1(
    const float* __restrict__ gP, const float* __restrict__ gS,
    float* __restrict__ gP2, float* __restrict__ gPS)
{
    int g = blockIdx.y;
    int row = blockIdx.x * 8 + (threadIdx.x >> 5);
    int cq = (threadIdx.x & 31) * 4;
    const float* P = gP + g * 16384;
    const float* S = gS + g * 16384;
    f4 a1 = {0.f,0.f,0.f,0.f}, a2 = {0.f,0.f,0.f,0.f};
    for (int k = 0; k < 128; k += 4) {
        f4 a = ld4(&P[row * 128 + k]);
        float av[4] = {a.x, a.y, a.z, a.w};
#pragma unroll
        for (int kk = 0; kk < 4; ++kk) {
            f4 b1 = ld4(&P[(k + kk) * 128 + cq]);
            f4 b2 = ld4(&S[(k + kk) * 128 + cq]);
            float aa = av[kk];
            a1.x += aa * b1.x; a1.y += aa * b1.y; a1.z += aa * b1.z; a1.w += aa * b1.w;
            a2.x += aa * b2.x; a2.y += aa * b2.y; a2.z += aa * b2.z; a2.w += aa * b2.w;
        }
    }
    *(f4*)&gP2[g * 16384 + row * 128 + cq] = a1;
    *(f4*)&gPS[g * 16384 + row * 128 + cq] = a2;
}

// ---------------- K5: P = 1.5P - 0.5*(P2@PS); final iter also emits bf16 W ----------------
__global__ __launch_bounds__(256) void k_ns2(
    float* __restrict__ gP, const float* __restrict__ gP2, const float* __restrict__ gPS,
    const float* __restrict__ gScale, ushort* __restrict__ gWb, int writeW)
{
    int g = blockIdx.y;
    int row = blockIdx.x * 8 + (threadIdx.x >> 5);
    int cq = (threadIdx.x & 31) * 4;
    const float* A = gP2 + g * 16384;
    const float* B = gPS + g * 16384;
    f4 acc = {0.f,0.f,0.f,0.f};
    for (int k = 0; k < 128; k += 4) {
        f4 a = ld4(&A[row * 128 + k]);
        float av[4] = {a.x, a.y, a.z, a.w};
#pragma unroll
        for (int kk = 0; kk < 4; ++kk) {
            f4 b = ld4(&B[(k + kk) * 128 + cq]);
            float aa = av[kk];
            acc.x += aa * b.x; acc.y += aa * b.y; acc.z += aa * b.z; acc.w += aa * b.w;
        }
    }
    size_t off = (size_t)g * 16384 + row * 128 + cq;
    f4 p = ld4(&gP[off]);
    f4 r;
    r.x = 1.5f * p.x - 0.5f * acc.x;
    r.y = 1.5f * p.y - 0.5f * acc.y;
    r.z = 1.5f * p.z - 0.5f * acc.z;
    r.w = 1.5f * p.w - 0.5f * acc.w;
    *(f4*)&gP[off] = r;
    if (writeW) {
        float sc = gScale[g];
        uint32_t lo = (uint32_t)f2bf(r.x * sc) | ((uint32_t)f2bf(r.y * sc) << 16);
        uint32_t hi = (uint32_t)f2bf(r.z * sc) | ((uint32_t)f2bf(r.w * sc) << 16);
        *(uint2*)&gWb[off] = make_uint2(lo, hi);
    }
}

// ---------------- K6: beta' = beta - gamma*(W@mu) ----------------
__global__ __launch_bounds__(128) void k_bprime(
    const float* __restrict__ gP, const float* __restrict__ gMean,
    const float* __restrict__ gScale, const float* __restrict__ gamma,
    const float* __restrict__ beta, float* __restrict__ gBp)
{
    int g = blockIdx.x, j = threadIdx.x;
    float s = 0.f;
    for (int k = 0; k < 128; ++k)
        s += gMean[g * 128 + k] * gP[g * 16384 + k * 128 + j];
    s *= gScale[g];
    int c = g * 128 + j;
    gBp[c] = beta[c] - gamma[c] * s;
}

// ---------------- K7: out = gamma*(bf16(X)@Wb) + beta'  (32x32x16 MFMA) ----------------
// grid (NTOT/128, 4), block 256 (4 waves; each wave 32 samples x 128 cols).
__global__ __launch_bounds__(256) void k_apply(
    const float* __restrict__ x, const ushort* __restrict__ gWb,
    const float* __restrict__ gamma, const float* __restrict__ gBp,
    float* __restrict__ out)
{
    const int g = blockIdx.y;
    const int t = threadIdx.x, lane = t & 63, w = t >> 6;
    const int l31 = lane & 31, hi = lane >> 5;
    const int s0 = blockIdx.x * 128 + w * 32;

    // ---- issue all A loads up front (16 x dwordx4 in flight) ----
    const float* ap = x + (size_t)(s0 + l31) * CTOT + g * MGRP + hi * 8;
    f4 a0[8], a1[8];
#pragma unroll
    for (int ks = 0; ks < 8; ++ks) {
        a0[ks] = ld4(ap + ks * 16);
        a1[ks] = ld4(ap + ks * 16 + 4);
    }

    float gm[4], bp[4];
#pragma unroll
    for (int ct = 0; ct < 4; ++ct) {
        int ch = g * MGRP + ct * 32 + l31;
        gm[ct] = gamma[ch];
        bp[ct] = gBp[ch];
    }

    bf16x8 af[8];
#pragma unroll
    for (int ks = 0; ks < 8; ++ks) {
        union { bf16x8 v; ushort u[8]; } cv;
        cv.u[0] = f2bf(a0[ks].x); cv.u[1] = f2bf(a0[ks].y);
        cv.u[2] = f2bf(a0[ks].z); cv.u[3] = f2bf(a0[ks].w);
        cv.u[4] = f2bf(a1[ks].x); cv.u[5] = f2bf(a1[ks].y);
        cv.u[6] = f2bf(a1[ks].z); cv.u[7] = f2bf(a1[ks].w);
        af[ks] = cv.v;
    }

    const ushort* Wg = gWb + g * 16384;
#pragma unroll
    for (int ct = 0; ct < 4; ++ct) {
        bf16x8 wf[8];
#pragma unroll
        for (int ks = 0; ks < 8; ++ks)   // W symmetric: row (ct*32+l31), k contiguous
            wf[ks] = *(const bf16x8*)&Wg[(ct*32 + l31) * 128 + ks*16 + hi*8];
        f32x16 acc = {};
#pragma unroll
        for (int ks = 0; ks < 8; ++ks)
            acc = __builtin_amdgcn_mfma_f32_32x32x16_bf16(af[ks], wf[ks], acc, 0, 0, 0);
#pragma unroll
        for (int r = 0; r < 16; ++r) {
            int row = s0 + (r & 3) + 8 * (r >> 2) + 4 * hi;
            float val = gm[ct] * acc[r] + bp[ct];
            __builtin_nontemporal_store(val, &out[(size_t)row * CTOT + g * MGRP + ct * 32 + l31]);
        }
    }
}

// ---------------- launch ----------------
extern "C" void kernel_launch(void* const* d_in, const int* in_sizes, int n_in,
                              void* d_out, int out_size, void* d_ws, size_t ws_size,
                              hipStream_t stream)
{
    const float* x     = (const float*)d_in[0];
    const float* gamma = (const float*)d_in[1];
    const float* beta  = (const float*)d_in[2];
    float* out = (float*)d_out;
    float* ws  = (float*)d_ws;

    int nchunk = 192;   // rowsPer must stay divisible by 64
    auto need = [](int nc) -> size_t {
        return ((size_t)nc * 4 * 16384 + (size_t)nc * 4 * 128 +
                5ull * 4 * 16384 + 512 + 16 + 512 + 32768) * 4;
    };
    while (nchunk > 12 && need(nchunk) > ws_size) nchunk >>= 1;
    int rowsPer = NTOT / nchunk;

    size_t off = 0;
    float* sxxPart = ws + off; off += (size_t)nchunk * 4 * 16384;
    float* sxPart  = ws + off; off += (size_t)nchunk * 4 * 128;
    float* gSxx    = ws + off; off += 4 * 16384;
    float* gSigma  = ws + off; off += 4 * 16384;
    float* gP      = ws + off; off += 4 * 16384;
    float* gP2     = ws + off; off += 4 * 16384;
    float* gPS     = ws + off; off += 4 * 16384;
    float* gMean   = ws + off; off += 512;
    float* gScale  = ws + off; off += 16;
    float* gBp     = ws + off; off += 512;
    ushort* gWb    = (ushort*)(ws + off); off += 32768;

    k_cov<<<dim3(nchunk, 4), 512, 0, stream>>>(x, sxxPart, sxPart, nchunk, rowsPer);
    k_reduce<<<dim3(64, 4), 256, 0, stream>>>(sxxPart, gSxx, nchunk);
    k_finalize<<<4, 256, 0, stream>>>(gSxx, sxPart, gSigma, gP, gMean, gScale, nchunk);
    k_ns1<<<dim3(16, 4), 256, 0, stream>>>(gP, gSigma, gP2, gPS);
    k_ns2<<<dim3(16, 4), 256, 0, stream>>>(gP, gP2, gPS, gScale, gWb, 0);
    k_ns1<<<dim3(16, 4), 256, 0, stream>>>(gP, gSigma, gP2, gPS);
    k_ns2<<<dim3(16, 4), 256, 0, stream>>>(gP, gP2, gPS, gScale, gWb, 1);
    k_bprime<<<4, 128, 0, stream>>>(gP, gMean, gScale, gamma, beta, gBp);
    k_apply<<<dim3(NTOT / 128, 4), 256, 0, stream>>>(x, gWb, gamma, gBp, out);
}

// Round 6
// 196.270 us; speedup vs baseline: 1.1194x; 1.1194x over previous
//
#include <hip/hip_runtime.h>
#include <cstdint>

#define NTOT 73728      // B*H*W = 32*48*48
#define CTOT 512
#define MGRP 128        // members per group
#define EPSV 1e-7f
#define LDP  72         // LDS row stride in bf16 (144 B: 16B-aligned, mild bank spread)

typedef float4 f4;
typedef __attribute__((ext_vector_type(8))) short bf16x8;   // 8 bf16 (4 VGPRs)
typedef __attribute__((ext_vector_type(4))) float f32x4;

__device__ __forceinline__ f4 ld4(const float* p){ return *(const f4*)p; }

__device__ __forceinline__ ushort f2bf(float f){  // RNE fp32 -> bf16
    uint32_t u = __builtin_bit_cast(uint32_t, f);
    uint32_t r = (u + 0x7FFFu + ((u >> 16) & 1u)) >> 16;
    return (ushort)r;
}

// ---------------- K1: Sxx partials (MFMA) + Sx partials + xb (bf16 x) ----------------
// grid (nchunk, 4), block 512 (8 waves, 2x4; wave tile 64x32 of 128x128 output).
// K-tile = 64 samples, double-buffered LDS [channel][sample] bf16, stride LDP.
__global__ __launch_bounds__(512) void k_cov(
    const float* __restrict__ x, float* __restrict__ sxxPart,
    float* __restrict__ sxPart, ushort* __restrict__ xb, int nchunk, int rowsPer)
{
    const int chunk = blockIdx.x, g = blockIdx.y;
    const int t = threadIdx.x;
    const int lane = t & 63, wid = t >> 6;
    const int wm = wid >> 2, wn = wid & 3;
    const int l15 = lane & 15, l4 = lane >> 4;

    __shared__ ushort xs[2][128 * LDP];   // 2 x 18,432 B
    __shared__ float sxbuf[512];

    const int c = t & 127;                // staging channel
    const int o = t >> 7;                 // octet id: handles octets o and o+4
    const size_t rowbase = (size_t)chunk * rowsPer;
    const float* xp = x + rowbase * CTOT + (size_t)g * MGRP + c;

    // xb writer mapping: ws_ = sample-in-tile, co/co+8 = channel-octets (16 ch/thread)
    const int ws_ = t >> 3;               // 0..63 sample
    const int co  = t & 7;                // 0..7 -> octets co and co+8
    ushort* xbp = xb + (rowbase + ws_) * CTOT + (size_t)g * MGRP + co * 8;

    f32x4 acc[4][2];
#pragma unroll
    for (int i = 0; i < 4; ++i)
#pragma unroll
        for (int j = 0; j < 2; ++j) acc[i][j] = (f32x4){0.f, 0.f, 0.f, 0.f};
    float sx = 0.f;

    float v[16];
#pragma unroll
    for (int e = 0; e < 8; ++e) {
        v[e]     = xp[(size_t)(o * 8 + e) * CTOT];
        v[8 + e] = xp[(size_t)((o + 4) * 8 + e) * CTOT];
    }

    const int niter = rowsPer / 64;
    int cur = 0;
    for (int it = 0; it < niter; ++it) {
        uint32_t pkA[4], pkB[4];
#pragma unroll
        for (int e = 0; e < 4; ++e) {
            sx += v[2*e] + v[2*e+1] + v[8+2*e] + v[8+2*e+1];
            pkA[e] = (uint32_t)f2bf(v[2*e])   | ((uint32_t)f2bf(v[2*e+1])   << 16);
            pkB[e] = (uint32_t)f2bf(v[8+2*e]) | ((uint32_t)f2bf(v[8+2*e+1]) << 16);
        }
        *(uint4*)&xs[cur][c * LDP + o * 8]       = make_uint4(pkA[0], pkA[1], pkA[2], pkA[3]);
        *(uint4*)&xs[cur][c * LDP + (o + 4) * 8] = make_uint4(pkB[0], pkB[1], pkB[2], pkB[3]);
        __syncthreads();                  // single barrier per iter (dbuf)
        if (it + 1 < niter) {
            const float* np = xp + (size_t)(it + 1) * 64 * CTOT;
#pragma unroll
            for (int e = 0; e < 8; ++e) {
                v[e]     = np[(size_t)(o * 8 + e) * CTOT];
                v[8 + e] = np[(size_t)((o + 4) * 8 + e) * CTOT];
            }
        }
#pragma unroll
        for (int kc = 0; kc < 2; ++kc) {
            bf16x8 af[4], bfr[2];
#pragma unroll
            for (int tm = 0; tm < 4; ++tm)
                af[tm] = *(const bf16x8*)&xs[cur][(wm*64 + tm*16 + l15) * LDP + kc*32 + l4*8];
#pragma unroll
            for (int tn = 0; tn < 2; ++tn)
                bfr[tn] = *(const bf16x8*)&xs[cur][(wn*32 + tn*16 + l15) * LDP + kc*32 + l4*8];
#pragma unroll
            for (int tm = 0; tm < 4; ++tm)
#pragma unroll
                for (int tn = 0; tn < 2; ++tn)
                    acc[tm][tn] = __builtin_amdgcn_mfma_f32_16x16x32_bf16(
                        af[tm], bfr[tn], acc[tm][tn], 0, 0, 0);
        }
        // emit xb tile: LDS is [channel][sample]; gather 16 channels of one sample
        {
            uint32_t pw[4], pw2[4];
#pragma unroll
            for (int e = 0; e < 4; ++e) {
                uint32_t lo  = xs[cur][(co*8 + 2*e)       * LDP + ws_];
                uint32_t hi  = xs[cur][(co*8 + 2*e + 1)   * LDP + ws_];
                pw[e]  = lo  | (hi  << 16);
                uint32_t lo2 = xs[cur][((co+8)*8 + 2*e)     * LDP + ws_];
                uint32_t hi2 = xs[cur][((co+8)*8 + 2*e + 1) * LDP + ws_];
                pw2[e] = lo2 | (hi2 << 16);
            }
            ushort* dst = xbp + (size_t)it * 64 * CTOT;
            *(uint4*)dst        = make_uint4(pw[0],  pw[1],  pw[2],  pw[3]);
            *(uint4*)(dst + 64) = make_uint4(pw2[0], pw2[1], pw2[2], pw2[3]);
        }
        cur ^= 1;
    }

    float* op = sxxPart + ((size_t)g * nchunk + chunk) * 16384;
#pragma unroll
    for (int tm = 0; tm < 4; ++tm)
#pragma unroll
        for (int tn = 0; tn < 2; ++tn)
#pragma unroll
            for (int r = 0; r < 4; ++r) {
                int i = wm*64 + tm*16 + l4*4 + r;
                int j = wn*32 + tn*16 + l15;
                op[i * 128 + j] = acc[tm][tn][r];
            }

    sxbuf[t] = sx;
    __syncthreads();
    if (t < 128) {
        float s = sxbuf[t] + sxbuf[t + 128] + sxbuf[t + 256] + sxbuf[t + 384];
        sxPart[((size_t)g * nchunk + chunk) * 128 + t] = s;
    }
}

// ---------------- K2: reduce Sxx partials over chunks ----------------
__global__ __launch_bounds__(256) void k_reduce(
    const float* __restrict__ sxxPart, float* __restrict__ gSxx, int nchunk)
{
    int g = blockIdx.y;
    int idx = blockIdx.x * 256 + threadIdx.x;
    float s = 0.f;
#pragma unroll 8
    for (int c = 0; c < nchunk; ++c)
        s += sxxPart[((size_t)g * nchunk + c) * 16384 + idx];
    gSxx[g * 16384 + idx] = s;
}

// ---------------- K3: finalize -> mean, trace, sigma, P1 ----------------
__global__ __launch_bounds__(256) void k_finalize(
    const float* __restrict__ gSxx, const float* __restrict__ sxPart,
    float* __restrict__ gSigma, float* __restrict__ gP,
    float* __restrict__ gMean, float* __restrict__ gScale, int nchunk)
{
    int g = blockIdx.x, t = threadIdx.x;
    __shared__ float mu[128];
    __shared__ float red[256];

    if (t < 128) {
        float s = 0.f;
        for (int c = 0; c < nchunk; ++c)
            s += sxPart[((size_t)g * nchunk + c) * 128 + t];
        float m = s / (float)NTOT;
        mu[t] = m;
        gMean[g * 128 + t] = m;
    }
    __syncthreads();

    float d = 0.f;
    if (t < 128) {
        float vdiag = gSxx[g * 16384 + t * 128 + t];
        float cv = (vdiag - (float)NTOT * mu[t] * mu[t]) / ((float)NTOT - 1.f);
        d = (1.f - EPSV) * cv + EPSV;
    }
    red[t] = d;
    __syncthreads();
    for (int s = 128; s > 0; s >>= 1) {
        if (t < s) red[t] += red[t + s];
        __syncthreads();
    }
    float tr = red[0];
    float invTr = 1.f / tr;
    if (t == 0) gScale[g] = rsqrtf(tr);

    for (int e = t; e < 16384; e += 256) {
        int i = e >> 7, j = e & 127;
        float cv = (gSxx[g * 16384 + e] - (float)NTOT * mu[i] * mu[j]) / ((float)NTOT - 1.f);
        float ce = (1.f - EPSV) * cv + ((i == j) ? EPSV : 0.f);
        float sg = ce * invTr;
        gSigma[g * 16384 + e] = sg;
        gP[g * 16384 + e] = ((i == j) ? 1.5f : 0.f) - 0.5f * sg;
    }
}

// ---------------- K4: P2 = P@P, PS = P@Sigma ----------------
__global__ __launch_bounds__(256) void k_ns1(
    const float* __restrict__ gP, const float* __restrict__ gS,
    float* __restrict__ gP2, float* __restrict__ gPS)
{
    int g = blockIdx.y;
    int row = blockIdx.x * 8 + (threadIdx.x >> 5);
    int cq = (threadIdx.x & 31) * 4;
    const float* P = gP + g * 16384;
    const float* S = gS + g * 16384;
    f4 a1 = {0.f,0.f,0.f,0.f}, a2 = {0.f,0.f,0.f,0.f};
    for (int k = 0; k < 128; k += 4) {
        f4 a = ld4(&P[row * 128 + k]);
        float av[4] = {a.x, a.y, a.z, a.w};
#pragma unroll
        for (int kk = 0; kk < 4; ++kk) {
            f4 b1 = ld4(&P[(k + kk) * 128 + cq]);
            f4 b2 = ld4(&S[(k + kk) * 128 + cq]);
            float aa = av[kk];
            a1.x += aa * b1.x; a1.y += aa * b1.y; a1.z += aa * b1.z; a1.w += aa * b1.w;
            a2.x += aa * b2.x; a2.y += aa * b2.y; a2.z += aa * b2.z; a2.w += aa * b2.w;
        }
    }
    *(f4*)&gP2[g * 16384 + row * 128 + cq] = a1;
    *(f4*)&gPS[g * 16384 + row * 128 + cq] = a2;
}

// ---------------- K5: P = 1.5P - 0.5*(P2@PS); final iter also emits bf16 W ----------------
__global__ __launch_bounds__(256) void k_ns2(
    float* __restrict__ gP, const float* __restrict__ gP2, const float* __restrict__ gPS,
    const float* __restrict__ gScale, ushort* __restrict__ gWb, int writeW)
{
    int g = blockIdx.y;
    int row = blockIdx.x * 8 + (threadIdx.x >> 5);
    int cq = (threadIdx.x & 31) * 4;
    const float* A = gP2 + g * 16384;
    const float* B = gPS + g * 16384;
    f4 acc = {0.f,0.f,0.f,0.f};
    for (int k = 0; k < 128; k += 4) {
        f4 a = ld4(&A[row * 128 + k]);
        float av[4] = {a.x, a.y, a.z, a.w};
#pragma unroll
        for (int kk = 0; kk < 4; ++kk) {
            f4 b = ld4(&B[(k + kk) * 128 + cq]);
            float aa = av[kk];
            acc.x += aa * b.x; acc.y += aa * b.y; acc.z += aa * b.z; acc.w += aa * b.w;
        }
    }
    size_t off = (size_t)g * 16384 + row * 128 + cq;
    f4 p = ld4(&gP[off]);
    f4 r;
    r.x = 1.5f * p.x - 0.5f * acc.x;
    r.y = 1.5f * p.y - 0.5f * acc.y;
    r.z = 1.5f * p.z - 0.5f * acc.z;
    r.w = 1.5f * p.w - 0.5f * acc.w;
    *(f4*)&gP[off] = r;
    if (writeW) {
        float sc = gScale[g];
        uint32_t lo = (uint32_t)f2bf(r.x * sc) | ((uint32_t)f2bf(r.y * sc) << 16);
        uint32_t hi = (uint32_t)f2bf(r.z * sc) | ((uint32_t)f2bf(r.w * sc) << 16);
        *(uint2*)&gWb[off] = make_uint2(lo, hi);
    }
}

// ---------------- K6: beta' = beta - gamma*(W@mu) ----------------
__global__ __launch_bounds__(128) void k_bprime(
    const float* __restrict__ gP, const float* __restrict__ gMean,
    const float* __restrict__ gScale, const float* __restrict__ gamma,
    const float* __restrict__ beta, float* __restrict__ gBp)
{
    int g = blockIdx.x, j = threadIdx.x;
    float s = 0.f;
    for (int k = 0; k < 128; ++k)
        s += gMean[g * 128 + k] * gP[g * 16384 + k * 128 + j];
    s *= gScale[g];
    int c = g * 128 + j;
    gBp[c] = beta[c] - gamma[c] * s;
}

// ---------------- K7: out = gamma*(xb @ Wb) + beta'  (16x16x32 MFMA, pipelined) ----------------
// grid (NTOT/256, 4), block 512 (8 waves: 4 sample-quads wm x 2 col-halves wn).
__global__ __launch_bounds__(512) void k_apply(
    const ushort* __restrict__ xb, const ushort* __restrict__ gWb,
    const float* __restrict__ gamma, const float* __restrict__ gBp,
    float* __restrict__ out)
{
    const int g = blockIdx.y;
    const int t = threadIdx.x, lane = t & 63, wid = t >> 6;
    const int wm = wid >> 1, wn = wid & 1;
    const int l15 = lane & 15, l4 = lane >> 4;
    const int s0 = blockIdx.x * 256 + wm * 64;

    // W fragments resident: B[k][j] = W[k][col]; W symmetric -> row-major loads.
    const ushort* Wg = gWb + g * 16384;
    bf16x8 wf[4][4];
#pragma unroll
    for (int kt = 0; kt < 4; ++kt)
#pragma unroll
        for (int tn = 0; tn < 4; ++tn)
            wf[kt][tn] = *(const bf16x8*)&Wg[(wn*64 + tn*16 + l15) * 128 + kt*32 + l4*8];

    float gm[4], bp[4];
#pragma unroll
    for (int tn = 0; tn < 4; ++tn) {
        int ch = g * MGRP + wn*64 + tn*16 + l15;
        gm[tn] = gamma[ch];
        bp[tn] = gBp[ch];
    }

    const ushort* ap = xb + (size_t)(s0 + l15) * CTOT + g * MGRP + l4*8;

    bf16x8 abufA[4], abufB[4];
#pragma unroll
    for (int kt = 0; kt < 4; ++kt)
        abufA[kt] = *(const bf16x8*)(ap + kt*32);          // tm=0 loads

#pragma unroll
    for (int tm = 0; tm < 4; ++tm) {
        // issue next tile's A loads into the other buffer (in flight during MFMA)
        if (tm < 3) {
            const ushort* np = ap + (size_t)(tm + 1) * 16 * CTOT;
            if (tm & 1) {
#pragma unroll
                for (int kt = 0; kt < 4; ++kt) abufA[kt] = *(const bf16x8*)(np + kt*32);
            } else {
#pragma unroll
                for (int kt = 0; kt < 4; ++kt) abufB[kt] = *(const bf16x8*)(np + kt*32);
            }
        }
        f32x4 acc[4];
#pragma unroll
        for (int tn = 0; tn < 4; ++tn) acc[tn] = (f32x4){0.f, 0.f, 0.f, 0.f};
#pragma unroll
        for (int tn = 0; tn < 4; ++tn)
#pragma unroll
            for (int kt = 0; kt < 4; ++kt)
                acc[tn] = __builtin_amdgcn_mfma_f32_16x16x32_bf16(
                    (tm & 1) ? abufB[kt] : abufA[kt], wf[kt][tn], acc[tn], 0, 0, 0);
#pragma unroll
        for (int tn = 0; tn < 4; ++tn)
#pragma unroll
            for (int r = 0; r < 4; ++r) {
                int row = s0 + tm*16 + l4*4 + r;
                float val = gm[tn] * acc[tn][r] + bp[tn];
                __builtin_nontemporal_store(val,
                    &out[(size_t)row * CTOT + g * MGRP + wn*64 + tn*16 + l15]);
            }
    }
}

// ---------------- launch ----------------
extern "C" void kernel_launch(void* const* d_in, const int* in_sizes, int n_in,
                              void* d_out, int out_size, void* d_ws, size_t ws_size,
                              hipStream_t stream)
{
    const float* x     = (const float*)d_in[0];
    const float* gamma = (const float*)d_in[1];
    const float* beta  = (const float*)d_in[2];
    float* out = (float*)d_out;
    float* ws  = (float*)d_ws;

    int nchunk = 128;   // rowsPer = 576 (divisible by 64)
    auto need = [](int nc) -> size_t {
        return ((size_t)nc * 4 * 16384 + (size_t)nc * 4 * 128 +
                5ull * 4 * 16384 + 512 + 16 + 512 + 32768 +
                (size_t)NTOT * CTOT / 2) * 4;
    };
    while (nchunk > 16 && need(nchunk) > ws_size) nchunk >>= 1;
    int rowsPer = NTOT / nchunk;

    size_t off = 0;
    float* sxxPart = ws + off; off += (size_t)nchunk * 4 * 16384;
    float* sxPart  = ws + off; off += (size_t)nchunk * 4 * 128;
    float* gSxx    = ws + off; off += 4 * 16384;
    float* gSigma  = ws + off; off += 4 * 16384;
    float* gP      = ws + off; off += 4 * 16384;
    float* gP2     = ws + off; off += 4 * 16384;
    float* gPS     = ws + off; off += 4 * 16384;
    float* gMean   = ws + off; off += 512;
    float* gScale  = ws + off; off += 16;
    float* gBp     = ws + off; off += 512;
    ushort* gWb    = (ushort*)(ws + off); off += 32768;   // 4*16384 bf16 = 32768 float-slots
    ushort* xb     = (ushort*)(ws + off); off += (size_t)NTOT * CTOT / 2;

    k_cov<<<dim3(nchunk, 4), 512, 0, stream>>>(x, sxxPart, sxPart, xb, nchunk, rowsPer);
    k_reduce<<<dim3(64, 4), 256, 0, stream>>>(sxxPart, gSxx, nchunk);
    k_finalize<<<4, 256, 0, stream>>>(gSxx, sxPart, gSigma, gP, gMean, gScale, nchunk);
    k_ns1<<<dim3(16, 4), 256, 0, stream>>>(gP, gSigma, gP2, gPS);
    k_ns2<<<dim3(16, 4), 256, 0, stream>>>(gP, gP2, gPS, gScale, gWb, 0);
    k_ns1<<<dim3(16, 4), 256, 0, stream>>>(gP, gSigma, gP2, gPS);
    k_ns2<<<dim3(16, 4), 256, 0, stream>>>(gP, gP2, gPS, gScale, gWb, 1);
    k_bprime<<<4, 128, 0, stream>>>(gP, gMean, gScale, gamma, beta, gBp);
    k_apply<<<dim3(NTOT / 256, 4), 512, 0, stream>>>(xb, gWb, gamma, gBp, out);
}